// Round 3
// baseline (606.013 us; speedup 1.0000x reference)
//
#include <hip/hip_runtime.h>
#include <math.h>

#define BM 128
#define BN 128
#define BK 64

typedef _Float16 f16x8 __attribute__((ext_vector_type(8)));
typedef __attribute__((ext_vector_type(4))) float f32x4;
typedef __attribute__((ext_vector_type(16))) float f32x16;

typedef const __attribute__((address_space(1))) void* gas_ptr;
typedef __attribute__((address_space(3))) void* las_ptr;

enum { OP_NONE = 0, OP_BIAS_GELU = 1, OP_BIAS = 2, OP_SCALE_MASK = 3 };

__device__ __forceinline__ unsigned short f2h(float f) {
    _Float16 h = (_Float16)f;  // RTNE
    unsigned short u;
    __builtin_memcpy(&u, &h, 2);
    return u;
}
__device__ __forceinline__ float h2f(unsigned short u) {
    _Float16 h;
    __builtin_memcpy(&h, &u, 2);
    return (float)h;
}

// tanh-form GELU via sigmoid: ~7 VALU instrs vs ~50 for libm erff.
// R6/R7 confirmed: absmax stays 0.03125 with this approximation.
__device__ __forceinline__ float fast_gelu(float x) {
    float x2 = x * x;
    float p  = x * (-1.5957691216f - 0.0713548164f * x2);  // = -2u
    float t  = __expf(p);                                  // e^{-2u}
    return x * __builtin_amdgcn_rcpf(1.0f + t);            // x * sigma(2u)
}

// C = A @ B, B given transposed (BT is [N][K] row-major). A [M][K], C [M][N].
// fp16 in/out, fp32 accumulate. BK=64 XOR-swizzled global_load_lds staging
// (0 bank conflicts). M-fastest grid -> same-XCD A-stripe reuse.
//
// R3: 32x32x16 MFMA (was 16x16x32). Same FLOPs in ~17% fewer MFMA cycles
// (8.07 cyc / 32K FLOP vs 4.85 / 16K) and half the MFMA instruction count;
// ds_read count unchanged. Per wave: 2x2 tiles of 32x32, acc 4x f32x16.
//  A/B frag (by analogy with the verified 16x16x32 mapping): lane l holds
//    row = l&31, k = (l>>5)*8 + e (8 contiguous f16 = 1 ds_read_b128).
//  C/D (HW-verified m74/m101): col = l&31, row = (reg&3)+8*(reg>>2)+4*(l>>5).
// Epilogue stores nt=0,1 back-to-back per (mt,reg): each pair fully dirties
// the 128B L2 line (R2 measured: line-complete order removes ALL write
// amplification; WRITE_SIZE hit the exact ideal).
// __launch_bounds__(256, 4): 4 blocks/CU co-residency hides prologue/epilogue
// (this inter-block overlap beat the 1-block/CU 256^2 8-phase at K=1024, R1/R2).
template <int EPI, bool CAUSAL_K, bool TRI, bool REVM>
__global__ __launch_bounds__(256, 4) void gemm_bt(
    const unsigned short* __restrict__ A,
    const unsigned short* __restrict__ BT,
    unsigned short* __restrict__ Cw,
    const float* __restrict__ bias0,
    const float* __restrict__ bias1,
    const float* __restrict__ bias2,
    int M, int N, int K,
    long long sA, long long sB, long long sC,
    float scale)
{
    __shared__ __align__(16) unsigned short As[BM * BK];
    __shared__ __align__(16) unsigned short Bs[BN * BK];

    const int tid  = threadIdx.x;
    const int wave = tid >> 6;
    const int lane = tid & 63;

    int bm, bn, z;
    if (TRI) {
        // unrank t -> (i, j), j <= i, t = i(i+1)/2 + j
        const int t = blockIdx.x;
        int i = (int)((sqrtf(8.0f * t + 1.0f) - 1.0f) * 0.5f);
        while ((i + 1) * (i + 2) / 2 <= t) i++;
        while (i * (i + 1) / 2 > t) i--;
        const int j = t - i * (i + 1) / 2;
        bm = i * BM;
        bn = j * BN;
        z  = blockIdx.y;
    } else {
        bm = (REVM ? (gridDim.x - 1 - blockIdx.x) : blockIdx.x) * BM;
        bn = blockIdx.y * BN;
        z  = blockIdx.z;
    }

    const unsigned short* Ab = A  + (long long)z * sA;
    const unsigned short* Bb = BT + (long long)z * sB;
    unsigned short*       Cb = Cw + (long long)z * sC;
    const float* bias = nullptr;
    if (EPI == OP_BIAS || EPI == OP_BIAS_GELU)
        bias = (z == 0) ? bias0 : (z == 1) ? bias1 : bias2;

    const int wm = (wave >> 1) * 64;  // wave's 64x64 quadrant
    const int wn = (wave & 1) * 64;

    f32x16 acc[2][2];
    #pragma unroll
    for (int i = 0; i < 2; i++)
        #pragma unroll
        for (int j = 0; j < 2; j++)
            #pragma unroll
            for (int r = 0; r < 16; r++)
                acc[i][j][r] = 0.f;

    int Keff = K;
    if (CAUSAL_K) {
        int kl = bm + BM;
        Keff = kl < K ? kl : K;
    }

    const int srow = lane >> 3;                          // row within 8-row slab
    const int gchw = ((lane & 7) ^ (srow & 7)) * 8;      // swizzled chunk, halfwords
    const int l31  = lane & 31;
    const int hi   = lane >> 5;

    // per-lane global staging pointers; advance by BK per iter
    const unsigned short* pA = Ab + (long long)(bm + wave * 32 + srow) * K + gchw;
    const unsigned short* pB = Bb + (long long)(bn + wave * 32 + srow) * K + gchw;
    const long long rstep = 8ll * K;  // 8 rows between the 4 slabs of a wave

    for (int k0 = 0; k0 < Keff; k0 += BK) {
        #pragma unroll
        for (int s = 0; s < 4; ++s) {
            const int t = wave * 4 + s;
            __builtin_amdgcn_global_load_lds((gas_ptr)(const void*)(pA + s * rstep),
                                             (las_ptr)(void*)&As[t * 512 + lane * 8],
                                             16, 0, 0);
            __builtin_amdgcn_global_load_lds((gas_ptr)(const void*)(pB + s * rstep),
                                             (las_ptr)(void*)&Bs[t * 512 + lane * 8],
                                             16, 0, 0);
        }
        pA += BK;
        pB += BK;
        __syncthreads();  // drains vmcnt -> staged data visible

        // LDS[r][c] holds global[r][c ^ (r&7)]; lane wants chunk ks*2+hi of
        // row (base + l31) -> ds-chunk = (ks*2+hi) ^ (row&7). Conflict-free
        // (8 lanes per 4-bank chunk group = 2-way, free per m136).
        #pragma unroll
        for (int ks = 0; ks < 4; ++ks) {
            f16x8 fa[2], fb[2];
            #pragma unroll
            for (int mt = 0; mt < 2; mt++) {
                const int row  = wm + mt * 32 + l31;
                const int slot = row * 8 + ((ks * 2 + hi) ^ (row & 7));
                fa[mt] = *(const f16x8*)&As[slot * 8];
            }
            #pragma unroll
            for (int nt = 0; nt < 2; nt++) {
                const int row  = wn + nt * 32 + l31;
                const int slot = row * 8 + ((ks * 2 + hi) ^ (row & 7));
                fb[nt] = *(const f16x8*)&Bs[slot * 8];
            }
            #pragma unroll
            for (int mt = 0; mt < 2; mt++)
                #pragma unroll
                for (int nt = 0; nt < 2; nt++)
                    acc[mt][nt] = __builtin_amdgcn_mfma_f32_32x32x16_f16(
                        fa[mt], fb[nt], acc[mt][nt], 0, 0, 0);
        }
        __syncthreads();  // protect LDS before next stage overwrites
    }

    // epilogue: 32x32 C/D layout col=l&31, row=(reg&3)+8*(reg>>2)+4*(l>>5).
    // nt=0,1 stored back-to-back per (mt,reg): lanes 0-31 cover cols [wn,wn+64)
    // of one row -> each 128B line fully dirtied before moving on.
    float bj[2];
    if (EPI == OP_BIAS || EPI == OP_BIAS_GELU) {
        #pragma unroll
        for (int nt = 0; nt < 2; nt++) bj[nt] = bias[bn + wn + nt * 32 + l31];
    }
    #pragma unroll
    for (int mt = 0; mt < 2; mt++) {
        #pragma unroll
        for (int r8 = 0; r8 < 4; r8++) {
            #pragma unroll
            for (int r4 = 0; r4 < 4; r4++) {
                const int reg = r8 * 4 + r4;
                const int row = bm + wm + mt * 32 + r4 + 8 * r8 + 4 * hi;
                #pragma unroll
                for (int nt = 0; nt < 2; nt++) {
                    const int col = bn + wn + nt * 32 + l31;
                    float v = acc[mt][nt][reg];
                    if (EPI == OP_BIAS_GELU) {
                        v = fast_gelu(v + bj[nt]);
                    } else if (EPI == OP_BIAS) {
                        v += bj[nt];
                    } else if (EPI == OP_SCALE_MASK) {
                        v *= scale;
                        if (col > row) v = 0.f;
                    }
                    Cb[(long long)row * N + col] = f2h(v);
                }
            }
        }
    }
}

// fp32 -> fp16 elementwise (n divisible by 1024)
__global__ __launch_bounds__(256) void cvt_f32_f16(
    const float4* __restrict__ in, ushort4* __restrict__ out)
{
    int i = blockIdx.x * 256 + threadIdx.x;
    float4 f = in[i];
    ushort4 o;
    o.x = f2h(f.x); o.y = f2h(f.y); o.z = f2h(f.z); o.w = f2h(f.w);
    out[i] = o;
}

// all six weight matrices: fp32 -> fp16 transposed, one dispatch (z=0..5).
__global__ __launch_bounds__(256) void wprep(
    const float* __restrict__ s0, const float* __restrict__ s1,
    const float* __restrict__ s2, const float* __restrict__ s3,
    const float* __restrict__ s4, const float* __restrict__ s5,
    unsigned short* __restrict__ W1T, unsigned short* __restrict__ W2T)
{
    const int C = 1024;
    const int z = blockIdx.z;
    const float* in = (z == 0) ? s0 : (z == 1) ? s1 : (z == 2) ? s2
                    : (z == 3) ? s3 : (z == 4) ? s4 : s5;
    unsigned short* out = (z < 3) ? (W1T + (long long)z * C * C)
                                  : (W2T + (long long)(z - 3) * C * C);
    __shared__ unsigned short tile[32][33];
    const int bx = blockIdx.x * 32;  // col base
    const int by = blockIdx.y * 32;  // row base
    const int x = threadIdx.x;
    for (int y = threadIdx.y; y < 32; y += 8)
        tile[y][x] = f2h(in[(long long)(by + y) * C + (bx + x)]);
    __syncthreads();
    for (int y = threadIdx.y; y < 32; y += 8)
        out[(long long)(bx + y) * C + (by + x)] = tile[x][y];
}

// wide fp16 transpose: 64x64 tiles, ushort4 (8B) loads AND stores.
// grid (cols/64, rows/64, NB); out[col][row] = in[row][col].
__global__ __launch_bounds__(256) void transpose64_f16(
    const unsigned short* __restrict__ in,
    unsigned short* __restrict__ out,
    int rows, int cols,
    long long sIn, long long sOut)
{
    __shared__ unsigned short tile[64][68];  // stride 68 shorts = 136 B (8B-aligned)
    const unsigned short* ip = in  + (long long)blockIdx.z * sIn;
    unsigned short*       op = out + (long long)blockIdx.z * sOut;
    const int bx = blockIdx.x * 64;  // col base
    const int by = blockIdx.y * 64;  // row base
    const int tid = threadIdx.x;
    const int rsub = tid >> 4;        // 0..15
    const int c4   = (tid & 15) * 4;  // 0,4,..,60
    #pragma unroll
    for (int it = 0; it < 4; it++) {
        const int r = it * 16 + rsub;
        ushort4 v = *(const ushort4*)&ip[(long long)(by + r) * cols + (bx + c4)];
        tile[r][c4]     = v.x;
        tile[r][c4 + 1] = v.y;
        tile[r][c4 + 2] = v.z;
        tile[r][c4 + 3] = v.w;
    }
    __syncthreads();
    #pragma unroll
    for (int it = 0; it < 4; it++) {
        const int cc = it * 16 + rsub;  // out row = in col
        ushort4 v;
        v.x = tile[c4][cc];
        v.y = tile[c4 + 1][cc];
        v.z = tile[c4 + 2][cc];
        v.w = tile[c4 + 3][cc];
        *(ushort4*)&op[(long long)(bx + cc) * rows + (by + c4)] = v;
    }
}

// one 256-thread block per row of 1024; fp16 in, fp32 params, fp32 out
__global__ __launch_bounds__(256) void layernorm_h(
    const unsigned short* __restrict__ X,
    const float* __restrict__ W,
    const float* __restrict__ Bv,
    float* __restrict__ Y)
{
    const int row = blockIdx.x;
    const int tid = threadIdx.x;
    ushort4 u = ((const ushort4*)(X + (long long)row * 1024))[tid];
    float f0 = h2f(u.x), f1 = h2f(u.y), f2 = h2f(u.z), f3 = h2f(u.w);
    float s  = f0 + f1 + f2 + f3;
    float ss = f0 * f0 + f1 * f1 + f2 * f2 + f3 * f3;
    #pragma unroll
    for (int off = 32; off > 0; off >>= 1) {
        s  += __shfl_down(s, off);
        ss += __shfl_down(ss, off);
    }
    __shared__ float red[2][4];
    const int wv = tid >> 6;
    if ((tid & 63) == 0) { red[0][wv] = s; red[1][wv] = ss; }
    __syncthreads();
    float S  = red[0][0] + red[0][1] + red[0][2] + red[0][3];
    float SS = red[1][0] + red[1][1] + red[1][2] + red[1][3];
    float mu  = S * (1.f / 1024.f);
    float var = SS * (1.f / 1024.f) - mu * mu;
    float rs  = rsqrtf(var + 1e-5f);
    float4 w4 = ((const float4*)W)[tid];
    float4 b4 = ((const float4*)Bv)[tid];
    float4 o;
    o.x = (f0 - mu) * rs * w4.x + b4.x;
    o.y = (f1 - mu) * rs * w4.y + b4.y;
    o.z = (f2 - mu) * rs * w4.z + b4.z;
    o.w = (f3 - mu) * rs * w4.w + b4.w;
    ((float4*)(Y + (long long)row * 1024))[tid] = o;
}

extern "C" void kernel_launch(void* const* d_in, const int* in_sizes, int n_in,
                              void* d_out, int out_size, void* d_ws, size_t ws_size,
                              hipStream_t stream)
{
    const int C  = 1024;
    const int T  = 2048;
    const int NB = 8;
    const int MT = NB * T;  // 16384 rows

    const float* x = (const float*)d_in[0];
    const float* W1q = (const float*)d_in[1];
    const float* b1q = (const float*)d_in[2];
    const float* W2q = (const float*)d_in[3];
    const float* b2q = (const float*)d_in[4];
    const float* W1k = (const float*)d_in[5];
    const float* b1k = (const float*)d_in[6];
    const float* W2k = (const float*)d_in[7];
    const float* b2k = (const float*)d_in[8];
    const float* W1v = (const float*)d_in[9];
    const float* b1v = (const float*)d_in[10];
    const float* W2v = (const float*)d_in[11];
    const float* b2v = (const float*)d_in[12];
    const float* lnw = (const float*)d_in[13];
    const float* lnb = (const float*)d_in[14];

    char* wsp = (char*)d_ws;
    auto take = [&](size_t bytes) {
        char* p = wsp;
        wsp += (bytes + 255) & ~(size_t)255;
        return p;
    };

    const size_t MATE = (size_t)MT * C;  // elements per [16384][1024] matrix

    unsigned short* W1T  = (unsigned short*)take((size_t)3 * C * C * 2);
    unsigned short* W2T  = (unsigned short*)take((size_t)3 * C * C * 2);
    unsigned short* xb   = (unsigned short*)take(MATE * 2);
    unsigned short* qkv  = (unsigned short*)take(3 * MATE * 2);  // q,k,v contiguous
    unsigned short* hreg = (unsigned short*)take(3 * MATE * 2);  // h; later scb+opre
    unsigned short* qb   = qkv;
    unsigned short* kb   = qkv + MATE;
    unsigned short* vb   = qkv + 2 * MATE;
    unsigned short* vT   = xb;                               // xb dead after MLP1
    unsigned short* scb  = hreg;                             // 8*T*T = 2*MATE elems
    unsigned short* opre = hreg + (size_t)NB * T * T;        // MATE elems — exact fit

    // x: fp32 -> fp16
    cvt_f32_f16<<<dim3(MT * C / 1024, 1, 1), dim3(256, 1, 1), 0, stream>>>(
        (const float4*)x, (ushort4*)xb);

    // all weights: fp32 -> fp16 transposed, one dispatch
    wprep<<<dim3(C / 32, C / 32, 6), dim3(32, 8, 1), 0, stream>>>(
        W1q, W1k, W1v, W2q, W2k, W2v, W1T, W2T);

    dim3 blk(256, 1, 1);

    // MLP GEMM1 (z = head): h_z = GELU(x @ W1_z + b1_z)   grid (M,N,z)
    gemm_bt<OP_BIAS_GELU, false, false, false><<<dim3(MT / BM, C / BN, 3), blk, 0, stream>>>(
        xb, W1T, hreg, b1q, b1k, b1v, MT, C, C,
        0, (long long)C * C, (long long)MATE, 1.f);

    // MLP GEMM2 (z = head): {q,k,v}_z = h_z @ W2_z + b2_z
    gemm_bt<OP_BIAS, false, false, false><<<dim3(MT / BM, C / BN, 3), blk, 0, stream>>>(
        hreg, W2T, qkv, b2q, b2k, b2v, MT, C, C,
        (long long)MATE, (long long)C * C, (long long)MATE, 1.f);

    // vT[b] = v[b]^T ([C][T] per batch) for the scores@v GEMM's BT operand
    transpose64_f16<<<dim3(C / 64, T / 64, NB), blk, 0, stream>>>(
        vb, vT, T, C, (long long)T * C, (long long)T * C);

    // scores = tril(q @ k^T) / sqrt(C*T); packed lower-triangle grid
    float inv_scale = 1.0f / sqrtf((float)C * (float)T);
    gemm_bt<OP_SCALE_MASK, false, true, false><<<dim3(136, NB, 1), blk, 0, stream>>>(
        qb, kb, scb, nullptr, nullptr, nullptr, T, T, C,
        (long long)T * C, (long long)T * C, (long long)T * T, inv_scale);

    // out_pre = scores @ v (K limited to bm+BM); longest-K blocks first (LPT)
    gemm_bt<OP_NONE, true, false, true><<<dim3(T / BM, C / BN, NB), blk, 0, stream>>>(
        scb, vT, opre, nullptr, nullptr, nullptr, T, C, T,
        (long long)T * T, (long long)T * C, (long long)T * C, 1.f);

    layernorm_h<<<dim3(MT, 1, 1), dim3(256, 1, 1), 0, stream>>>(
        opre, lnw, lnb, (float*)d_out);
}

// Round 4
// 538.775 us; speedup vs baseline: 1.1248x; 1.1248x over previous
//
#include <hip/hip_runtime.h>
#include <math.h>

#define BM 128
#define BN 128
#define BK 64

typedef _Float16 f16x8 __attribute__((ext_vector_type(8)));
typedef __attribute__((ext_vector_type(4))) float f32x4;

typedef const __attribute__((address_space(1))) void* gas_ptr;
typedef __attribute__((address_space(3))) void* las_ptr;

enum { OP_NONE = 0, OP_BIAS_GELU = 1, OP_BIAS = 2, OP_SCALE_MASK = 3 };

__device__ __forceinline__ unsigned short f2h(float f) {
    _Float16 h = (_Float16)f;  // RTNE
    unsigned short u;
    __builtin_memcpy(&u, &h, 2);
    return u;
}
__device__ __forceinline__ float h2f(unsigned short u) {
    _Float16 h;
    __builtin_memcpy(&h, &u, 2);
    return (float)h;
}

// tanh-form GELU via sigmoid: ~7 VALU instrs vs ~50 for libm erff.
// R6/R7 confirmed: absmax stays 0.03125 with this approximation.
__device__ __forceinline__ float fast_gelu(float x) {
    float x2 = x * x;
    float p  = x * (-1.5957691216f - 0.0713548164f * x2);  // = -2u
    float t  = __expf(p);                                  // e^{-2u}
    return x * __builtin_amdgcn_rcpf(1.0f + t);            // x * sigma(2u)
}

// C = A @ B, B given transposed (BT is [N][K] row-major). A [M][K], C [M][N].
// fp16 in/out, fp32 accumulate. BK=64 XOR-swizzled global_load_lds staging
// (0 bank conflicts). M-fastest grid -> same-XCD A-stripe reuse.
// 16x16x32 MFMA: this session's A/B on MFMA shape (R3) showed the 32x32x16
// fragment-read pattern costs 1.26e7 bank conflicts/dispatch (+21% dur) under
// the same XOR swizzle -- the 16x16 fr/quad pattern is the conflict-free one.
// Direct scatter epilogue with j INNERMOST (R2-validated on gemm256: each
// (i,r) completes its 128B L2 line -> WRITE_SIZE landed at the exact ideal;
// j-outer had 1.46x write amplification from partial-line evictions).
// __launch_bounds__(256, 4): 4 blocks/CU co-residency hides prologue/epilogue
// and the per-K-step barrier drain (m114 co-scheduling); this beat the
// 1-block/CU 256^2 8-phase schedule at K=1024 (R1/R2).
template <int EPI, bool CAUSAL_K, bool TRI, bool REVM>
__global__ __launch_bounds__(256, 4) void gemm_bt(
    const unsigned short* __restrict__ A,
    const unsigned short* __restrict__ BT,
    unsigned short* __restrict__ Cw,
    const float* __restrict__ bias0,
    const float* __restrict__ bias1,
    const float* __restrict__ bias2,
    int M, int N, int K,
    long long sA, long long sB, long long sC,
    float scale)
{
    __shared__ __align__(16) unsigned short As[BM * BK];
    __shared__ __align__(16) unsigned short Bs[BN * BK];

    const int tid  = threadIdx.x;
    const int wave = tid >> 6;
    const int lane = tid & 63;

    int bm, bn, z;
    if (TRI) {
        // unrank t -> (i, j), j <= i, t = i(i+1)/2 + j
        const int t = blockIdx.x;
        int i = (int)((sqrtf(8.0f * t + 1.0f) - 1.0f) * 0.5f);
        while ((i + 1) * (i + 2) / 2 <= t) i++;
        while (i * (i + 1) / 2 > t) i--;
        const int j = t - i * (i + 1) / 2;
        bm = i * BM;
        bn = j * BN;
        z  = blockIdx.y;
    } else {
        bm = (REVM ? (gridDim.x - 1 - blockIdx.x) : blockIdx.x) * BM;
        bn = blockIdx.y * BN;
        z  = blockIdx.z;
    }

    const unsigned short* Ab = A  + (long long)z * sA;
    const unsigned short* Bb = BT + (long long)z * sB;
    unsigned short*       Cb = Cw + (long long)z * sC;
    const float* bias = nullptr;
    if (EPI == OP_BIAS || EPI == OP_BIAS_GELU)
        bias = (z == 0) ? bias0 : (z == 1) ? bias1 : bias2;

    const int wm = (wave >> 1) * 64;  // wave's 64x64 quadrant
    const int wn = (wave & 1) * 64;

    f32x4 acc[4][4];
    #pragma unroll
    for (int i = 0; i < 4; i++)
        #pragma unroll
        for (int j = 0; j < 4; j++)
            acc[i][j] = (f32x4){0.f, 0.f, 0.f, 0.f};

    int Keff = K;
    if (CAUSAL_K) {
        int kl = bm + BM;
        Keff = kl < K ? kl : K;
    }

    const int srow = lane >> 3;                          // row within 8-row slab
    const int gchw = ((lane & 7) ^ (srow & 7)) * 8;      // swizzled chunk, halfwords
    const int fr   = lane & 15;
    const int quad = lane >> 4;

    // per-lane global staging pointers; advance by BK per iter
    const unsigned short* pA = Ab + (long long)(bm + wave * 32 + srow) * K + gchw;
    const unsigned short* pB = Bb + (long long)(bn + wave * 32 + srow) * K + gchw;
    const long long rstep = 8ll * K;  // 8 rows between the 4 slabs of a wave

    for (int k0 = 0; k0 < Keff; k0 += BK) {
        #pragma unroll
        for (int s = 0; s < 4; ++s) {
            const int t = wave * 4 + s;
            __builtin_amdgcn_global_load_lds((gas_ptr)(const void*)(pA + s * rstep),
                                             (las_ptr)(void*)&As[t * 512 + lane * 8],
                                             16, 0, 0);
            __builtin_amdgcn_global_load_lds((gas_ptr)(const void*)(pB + s * rstep),
                                             (las_ptr)(void*)&Bs[t * 512 + lane * 8],
                                             16, 0, 0);
        }
        pA += BK;
        pB += BK;
        __syncthreads();  // drains vmcnt -> staged data visible

        #pragma unroll
        for (int kk = 0; kk < 2; ++kk) {
            f16x8 fa[4], fb[4];
            #pragma unroll
            for (int i = 0; i < 4; i++) {
                const int row  = wm + i * 16 + fr;
                const int slot = row * 8 + ((kk * 4 + quad) ^ (fr & 7));
                fa[i] = *(const f16x8*)&As[slot * 8];
            }
            #pragma unroll
            for (int j = 0; j < 4; j++) {
                const int row  = wn + j * 16 + fr;
                const int slot = row * 8 + ((kk * 4 + quad) ^ (fr & 7));
                fb[j] = *(const f16x8*)&Bs[slot * 8];
            }
            #pragma unroll
            for (int i = 0; i < 4; i++)
                #pragma unroll
                for (int j = 0; j < 4; j++)
                    acc[i][j] = __builtin_amdgcn_mfma_f32_16x16x32_f16(
                        fa[i], fb[j], acc[i][j], 0, 0, 0);
        }
        __syncthreads();  // protect LDS before next stage overwrites
    }

    // epilogue: C/D layout col=lane&15, row=(lane>>4)*4+reg  [m89/m91]
    // j INNERMOST (R2-validated): per (i,r), lanes cover cols [wn, wn+64) in
    // 4 consecutive 32B stores -> each 128B L2 line fully dirtied immediately.
    const int er = quad;
    const int ec = fr;
    float bj[4];
    if (EPI == OP_BIAS || EPI == OP_BIAS_GELU) {
        #pragma unroll
        for (int j = 0; j < 4; j++) bj[j] = bias[bn + wn + j * 16 + ec];
    }
    #pragma unroll
    for (int i = 0; i < 4; i++) {
        #pragma unroll
        for (int r = 0; r < 4; r++) {
            const int row = bm + wm + i * 16 + er * 4 + r;
            #pragma unroll
            for (int j = 0; j < 4; j++) {
                const int col = bn + wn + j * 16 + ec;
                float v = acc[i][j][r];
                if (EPI == OP_BIAS_GELU) {
                    v = fast_gelu(v + bj[j]);
                } else if (EPI == OP_BIAS) {
                    v += bj[j];
                } else if (EPI == OP_SCALE_MASK) {
                    v *= scale;
                    if (col > row) v = 0.f;
                }
                Cb[(long long)row * N + col] = f2h(v);
            }
        }
    }
}

// fp32 -> fp16 elementwise (n divisible by 1024)
__global__ __launch_bounds__(256) void cvt_f32_f16(
    const float4* __restrict__ in, ushort4* __restrict__ out)
{
    int i = blockIdx.x * 256 + threadIdx.x;
    float4 f = in[i];
    ushort4 o;
    o.x = f2h(f.x); o.y = f2h(f.y); o.z = f2h(f.z); o.w = f2h(f.w);
    out[i] = o;
}

// all six weight matrices: fp32 -> fp16 transposed, one dispatch (z=0..5).
__global__ __launch_bounds__(256) void wprep(
    const float* __restrict__ s0, const float* __restrict__ s1,
    const float* __restrict__ s2, const float* __restrict__ s3,
    const float* __restrict__ s4, const float* __restrict__ s5,
    unsigned short* __restrict__ W1T, unsigned short* __restrict__ W2T)
{
    const int C = 1024;
    const int z = blockIdx.z;
    const float* in = (z == 0) ? s0 : (z == 1) ? s1 : (z == 2) ? s2
                    : (z == 3) ? s3 : (z == 4) ? s4 : s5;
    unsigned short* out = (z < 3) ? (W1T + (long long)z * C * C)
                                  : (W2T + (long long)(z - 3) * C * C);
    __shared__ unsigned short tile[32][33];
    const int bx = blockIdx.x * 32;  // col base
    const int by = blockIdx.y * 32;  // row base
    const int x = threadIdx.x;
    for (int y = threadIdx.y; y < 32; y += 8)
        tile[y][x] = f2h(in[(long long)(by + y) * C + (bx + x)]);
    __syncthreads();
    for (int y = threadIdx.y; y < 32; y += 8)
        out[(long long)(bx + y) * C + (by + x)] = tile[x][y];
}

// wide fp16 transpose: 64x64 tiles, ushort4 (8B) loads AND stores.
// grid (cols/64, rows/64, NB); out[col][row] = in[row][col].
__global__ __launch_bounds__(256) void transpose64_f16(
    const unsigned short* __restrict__ in,
    unsigned short* __restrict__ out,
    int rows, int cols,
    long long sIn, long long sOut)
{
    __shared__ unsigned short tile[64][68];  // stride 68 shorts = 136 B (8B-aligned)
    const unsigned short* ip = in  + (long long)blockIdx.z * sIn;
    unsigned short*       op = out + (long long)blockIdx.z * sOut;
    const int bx = blockIdx.x * 64;  // col base
    const int by = blockIdx.y * 64;  // row base
    const int tid = threadIdx.x;
    const int rsub = tid >> 4;        // 0..15
    const int c4   = (tid & 15) * 4;  // 0,4,..,60
    #pragma unroll
    for (int it = 0; it < 4; it++) {
        const int r = it * 16 + rsub;
        ushort4 v = *(const ushort4*)&ip[(long long)(by + r) * cols + (bx + c4)];
        tile[r][c4]     = v.x;
        tile[r][c4 + 1] = v.y;
        tile[r][c4 + 2] = v.z;
        tile[r][c4 + 3] = v.w;
    }
    __syncthreads();
    #pragma unroll
    for (int it = 0; it < 4; it++) {
        const int cc = it * 16 + rsub;  // out row = in col
        ushort4 v;
        v.x = tile[c4][cc];
        v.y = tile[c4 + 1][cc];
        v.z = tile[c4 + 2][cc];
        v.w = tile[c4 + 3][cc];
        *(ushort4*)&op[(long long)(bx + cc) * rows + (by + c4)] = v;
    }
}

// one 256-thread block per row of 1024; fp16 in, fp32 params, fp32 out
__global__ __launch_bounds__(256) void layernorm_h(
    const unsigned short* __restrict__ X,
    const float* __restrict__ W,
    const float* __restrict__ Bv,
    float* __restrict__ Y)
{
    const int row = blockIdx.x;
    const int tid = threadIdx.x;
    ushort4 u = ((const ushort4*)(X + (long long)row * 1024))[tid];
    float f0 = h2f(u.x), f1 = h2f(u.y), f2 = h2f(u.z), f3 = h2f(u.w);
    float s  = f0 + f1 + f2 + f3;
    float ss = f0 * f0 + f1 * f1 + f2 * f2 + f3 * f3;
    #pragma unroll
    for (int off = 32; off > 0; off >>= 1) {
        s  += __shfl_down(s, off);
        ss += __shfl_down(ss, off);
    }
    __shared__ float red[2][4];
    const int wv = tid >> 6;
    if ((tid & 63) == 0) { red[0][wv] = s; red[1][wv] = ss; }
    __syncthreads();
    float S  = red[0][0] + red[0][1] + red[0][2] + red[0][3];
    float SS = red[1][0] + red[1][1] + red[1][2] + red[1][3];
    float mu  = S * (1.f / 1024.f);
    float var = SS * (1.f / 1024.f) - mu * mu;
    float rs  = rsqrtf(var + 1e-5f);
    float4 w4 = ((const float4*)W)[tid];
    float4 b4 = ((const float4*)Bv)[tid];
    float4 o;
    o.x = (f0 - mu) * rs * w4.x + b4.x;
    o.y = (f1 - mu) * rs * w4.y + b4.y;
    o.z = (f2 - mu) * rs * w4.z + b4.z;
    o.w = (f3 - mu) * rs * w4.w + b4.w;
    ((float4*)(Y + (long long)row * 1024))[tid] = o;
}

extern "C" void kernel_launch(void* const* d_in, const int* in_sizes, int n_in,
                              void* d_out, int out_size, void* d_ws, size_t ws_size,
                              hipStream_t stream)
{
    const int C  = 1024;
    const int T  = 2048;
    const int NB = 8;
    const int MT = NB * T;  // 16384 rows

    const float* x = (const float*)d_in[0];
    const float* W1q = (const float*)d_in[1];
    const float* b1q = (const float*)d_in[2];
    const float* W2q = (const float*)d_in[3];
    const float* b2q = (const float*)d_in[4];
    const float* W1k = (const float*)d_in[5];
    const float* b1k = (const float*)d_in[6];
    const float* W2k = (const float*)d_in[7];
    const float* b2k = (const float*)d_in[8];
    const float* W1v = (const float*)d_in[9];
    const float* b1v = (const float*)d_in[10];
    const float* W2v = (const float*)d_in[11];
    const float* b2v = (const float*)d_in[12];
    const float* lnw = (const float*)d_in[13];
    const float* lnb = (const float*)d_in[14];

    char* wsp = (char*)d_ws;
    auto take = [&](size_t bytes) {
        char* p = wsp;
        wsp += (bytes + 255) & ~(size_t)255;
        return p;
    };

    const size_t MATE = (size_t)MT * C;  // elements per [16384][1024] matrix

    unsigned short* W1T  = (unsigned short*)take((size_t)3 * C * C * 2);
    unsigned short* W2T  = (unsigned short*)take((size_t)3 * C * C * 2);
    unsigned short* xb   = (unsigned short*)take(MATE * 2);
    unsigned short* qkv  = (unsigned short*)take(3 * MATE * 2);  // q,k,v contiguous
    unsigned short* hreg = (unsigned short*)take(3 * MATE * 2);  // h; later scb+opre
    unsigned short* qb   = qkv;
    unsigned short* kb   = qkv + MATE;
    unsigned short* vb   = qkv + 2 * MATE;
    unsigned short* vT   = xb;                               // xb dead after MLP1
    unsigned short* scb  = hreg;                             // 8*T*T = 2*MATE elems
    unsigned short* opre = hreg + (size_t)NB * T * T;        // MATE elems — exact fit

    // x: fp32 -> fp16
    cvt_f32_f16<<<dim3(MT * C / 1024, 1, 1), dim3(256, 1, 1), 0, stream>>>(
        (const float4*)x, (ushort4*)xb);

    // all weights: fp32 -> fp16 transposed, one dispatch
    wprep<<<dim3(C / 32, C / 32, 6), dim3(32, 8, 1), 0, stream>>>(
        W1q, W1k, W1v, W2q, W2k, W2v, W1T, W2T);

    dim3 blk(256, 1, 1);

    // MLP GEMM1 (z = head): h_z = GELU(x @ W1_z + b1_z)   grid (M,N,z)
    gemm_bt<OP_BIAS_GELU, false, false, false><<<dim3(MT / BM, C / BN, 3), blk, 0, stream>>>(
        xb, W1T, hreg, b1q, b1k, b1v, MT, C, C,
        0, (long long)C * C, (long long)MATE, 1.f);

    // MLP GEMM2 (z = head): {q,k,v}_z = h_z @ W2_z + b2_z
    gemm_bt<OP_BIAS, false, false, false><<<dim3(MT / BM, C / BN, 3), blk, 0, stream>>>(
        hreg, W2T, qkv, b2q, b2k, b2v, MT, C, C,
        (long long)MATE, (long long)C * C, (long long)MATE, 1.f);

    // vT[b] = v[b]^T ([C][T] per batch) for the scores@v GEMM's BT operand
    transpose64_f16<<<dim3(C / 64, T / 64, NB), blk, 0, stream>>>(
        vb, vT, T, C, (long long)T * C, (long long)T * C);

    // scores = tril(q @ k^T) / sqrt(C*T); packed lower-triangle grid
    float inv_scale = 1.0f / sqrtf((float)C * (float)T);
    gemm_bt<OP_SCALE_MASK, false, true, false><<<dim3(136, NB, 1), blk, 0, stream>>>(
        qb, kb, scb, nullptr, nullptr, nullptr, T, T, C,
        (long long)T * C, (long long)T * C, (long long)T * T, inv_scale);

    // out_pre = scores @ v (K limited to bm+BM); longest-K blocks first (LPT)
    gemm_bt<OP_NONE, true, false, true><<<dim3(T / BM, C / BN, NB), blk, 0, stream>>>(
        scb, vT, opre, nullptr, nullptr, nullptr, T, C, T,
        (long long)T * T, (long long)T * C, (long long)T * C, 1.f);

    layernorm_h<<<dim3(MT, 1, 1), dim3(256, 1, 1), 0, stream>>>(
        opre, lnw, lnb, (float*)d_out);
}

// Round 5
// 531.317 us; speedup vs baseline: 1.1406x; 1.0140x over previous
//
#include <hip/hip_runtime.h>
#include <math.h>

#define BM 128
#define BN 128
#define BK 64

typedef _Float16 f16x8 __attribute__((ext_vector_type(8)));
typedef __attribute__((ext_vector_type(4))) float f32x4;

typedef const __attribute__((address_space(1))) void* gas_ptr;
typedef __attribute__((address_space(3))) void* las_ptr;

enum { OP_NONE = 0, OP_BIAS_GELU = 1, OP_BIAS = 2, OP_SCALE_MASK = 3 };

__device__ __forceinline__ unsigned short f2h(float f) {
    _Float16 h = (_Float16)f;  // RTNE
    unsigned short u;
    __builtin_memcpy(&u, &h, 2);
    return u;
}
__device__ __forceinline__ float h2f(unsigned short u) {
    _Float16 h;
    __builtin_memcpy(&h, &u, 2);
    return (float)h;
}

// tanh-form GELU via sigmoid: ~7 VALU instrs vs ~50 for libm erff.
// Confirmed: absmax stays 0.03125 with this approximation.
__device__ __forceinline__ float fast_gelu(float x) {
    float x2 = x * x;
    float p  = x * (-1.5957691216f - 0.0713548164f * x2);  // = -2u
    float t  = __expf(p);                                  // e^{-2u}
    return x * __builtin_amdgcn_rcpf(1.0f + t);            // x * sigma(2u)
}

// C = A @ B, B given transposed (BT is [N][K] row-major). A [M][K], C [M][N].
// fp16 in/out, fp32 accumulate. BK=64 XOR-swizzled global_load_lds staging
// (0 bank conflicts). 16x16x32 MFMA (R3 A/B: 32x32x16 frag reads cost 1.26e7
// bank conflicts/dispatch, +21% dur -- 16x16 fr/quad is the conflict-free
// pattern). j-INNERMOST epilogue (R2/R4-validated: WRITE_SIZE at exact ideal,
// MLP 114->108 us; j-outer had 1.46x write amplification).
//
// PAIRM (R5): for the causal scores@v GEMM, 1024 blocks are exactly one
// co-resident round and block->CU aliasing (idx mod 256) gives each CU 4
// blocks with the SAME bx hence the SAME Keff -> 8:1 per-CU work spread;
// dispatch time = worst CU. Pairing bm=p with bm=15-p inside one block makes
// per-block work constant (17*128 = 2176 K-rows) -- balanced by construction,
// independent of how HW assigns blocks to CUs.
template <int EPI, bool CAUSAL_K, bool TRI, bool REVM, bool PAIRM>
__global__ __launch_bounds__(256, 4) void gemm_bt(
    const unsigned short* __restrict__ A,
    const unsigned short* __restrict__ BT,
    unsigned short* __restrict__ Cw,
    const float* __restrict__ bias0,
    const float* __restrict__ bias1,
    const float* __restrict__ bias2,
    int M, int N, int K,
    long long sA, long long sB, long long sC,
    float scale)
{
    __shared__ __align__(16) unsigned short As[BM * BK];
    __shared__ __align__(16) unsigned short Bs[BN * BK];

    const int tid  = threadIdx.x;
    const int wave = tid >> 6;
    const int lane = tid & 63;

    const int wm = (wave >> 1) * 64;  // wave's 64x64 quadrant
    const int wn = (wave & 1) * 64;

    const int srow = lane >> 3;                          // row within 8-row slab
    const int gchw = ((lane & 7) ^ (srow & 7)) * 8;      // swizzled chunk, halfwords
    const int fr   = lane & 15;
    const int quad = lane >> 4;

    const int nhalf = PAIRM ? 2 : 1;
    #pragma unroll 1
    for (int half = 0; half < nhalf; ++half) {
        int bm, bn, z;
        if (TRI) {
            // unrank t -> (i, j), j <= i, t = i(i+1)/2 + j
            const int t = blockIdx.x;
            int i = (int)((sqrtf(8.0f * t + 1.0f) - 1.0f) * 0.5f);
            while ((i + 1) * (i + 2) / 2 <= t) i++;
            while (i * (i + 1) / 2 > t) i--;
            const int j = t - i * (i + 1) / 2;
            bm = i * BM;
            bn = j * BN;
            z  = blockIdx.y;
        } else if (PAIRM) {
            // complementary pair: Keff sums to (2*gridDim.x + 1)*BM = const
            const int mb = half ? (2 * (int)gridDim.x - 1 - (int)blockIdx.x)
                                : (int)blockIdx.x;
            bm = mb * BM;
            bn = blockIdx.y * BN;
            z  = blockIdx.z;
        } else {
            bm = (REVM ? (gridDim.x - 1 - blockIdx.x) : blockIdx.x) * BM;
            bn = blockIdx.y * BN;
            z  = blockIdx.z;
        }

        const unsigned short* Ab = A  + (long long)z * sA;
        const unsigned short* Bb = BT + (long long)z * sB;
        unsigned short*       Cb = Cw + (long long)z * sC;
        const float* bias = nullptr;
        if (EPI == OP_BIAS || EPI == OP_BIAS_GELU)
            bias = (z == 0) ? bias0 : (z == 1) ? bias1 : bias2;

        f32x4 acc[4][4];
        #pragma unroll
        for (int i = 0; i < 4; i++)
            #pragma unroll
            for (int j = 0; j < 4; j++)
                acc[i][j] = (f32x4){0.f, 0.f, 0.f, 0.f};

        int Keff = K;
        if (CAUSAL_K) {
            int kl = bm + BM;
            Keff = kl < K ? kl : K;
        }

        // per-lane global staging pointers; advance by BK per iter
        const unsigned short* pA = Ab + (long long)(bm + wave * 32 + srow) * K + gchw;
        const unsigned short* pB = Bb + (long long)(bn + wave * 32 + srow) * K + gchw;
        const long long rstep = 8ll * K;  // 8 rows between the 4 slabs of a wave

        for (int k0 = 0; k0 < Keff; k0 += BK) {
            #pragma unroll
            for (int s = 0; s < 4; ++s) {
                const int t = wave * 4 + s;
                __builtin_amdgcn_global_load_lds((gas_ptr)(const void*)(pA + s * rstep),
                                                 (las_ptr)(void*)&As[t * 512 + lane * 8],
                                                 16, 0, 0);
                __builtin_amdgcn_global_load_lds((gas_ptr)(const void*)(pB + s * rstep),
                                                 (las_ptr)(void*)&Bs[t * 512 + lane * 8],
                                                 16, 0, 0);
            }
            pA += BK;
            pB += BK;
            __syncthreads();  // drains vmcnt -> staged data visible

            #pragma unroll
            for (int kk = 0; kk < 2; ++kk) {
                f16x8 fa[4], fb[4];
                #pragma unroll
                for (int i = 0; i < 4; i++) {
                    const int row  = wm + i * 16 + fr;
                    const int slot = row * 8 + ((kk * 4 + quad) ^ (fr & 7));
                    fa[i] = *(const f16x8*)&As[slot * 8];
                }
                #pragma unroll
                for (int j = 0; j < 4; j++) {
                    const int row  = wn + j * 16 + fr;
                    const int slot = row * 8 + ((kk * 4 + quad) ^ (fr & 7));
                    fb[j] = *(const f16x8*)&Bs[slot * 8];
                }
                #pragma unroll
                for (int i = 0; i < 4; i++)
                    #pragma unroll
                    for (int j = 0; j < 4; j++)
                        acc[i][j] = __builtin_amdgcn_mfma_f32_16x16x32_f16(
                            fa[i], fb[j], acc[i][j], 0, 0, 0);
            }
            __syncthreads();  // protect LDS before next stage overwrites
        }

        // epilogue: C/D layout col=lane&15, row=(lane>>4)*4+reg  [m89/m91]
        // j INNERMOST: per (i,r), lanes cover cols [wn, wn+64) in 4 consecutive
        // 32B stores -> each 128B L2 line fully dirtied immediately.
        const int er = quad;
        const int ec = fr;
        float bj[4];
        if (EPI == OP_BIAS || EPI == OP_BIAS_GELU) {
            #pragma unroll
            for (int j = 0; j < 4; j++) bj[j] = bias[bn + wn + j * 16 + ec];
        }
        #pragma unroll
        for (int i = 0; i < 4; i++) {
            #pragma unroll
            for (int r = 0; r < 4; r++) {
                const int row = bm + wm + i * 16 + er * 4 + r;
                #pragma unroll
                for (int j = 0; j < 4; j++) {
                    const int col = bn + wn + j * 16 + ec;
                    float v = acc[i][j][r];
                    if (EPI == OP_BIAS_GELU) {
                        v = fast_gelu(v + bj[j]);
                    } else if (EPI == OP_BIAS) {
                        v += bj[j];
                    } else if (EPI == OP_SCALE_MASK) {
                        v *= scale;
                        if (col > row) v = 0.f;
                    }
                    Cb[(long long)row * N + col] = f2h(v);
                }
            }
        }
        // LDS reuse across halves is race-free: last ds_reads precede the
        // K-loop's final __syncthreads; epilogue touches no LDS.
    }
}

// fp32 -> fp16 elementwise (n divisible by 1024)
__global__ __launch_bounds__(256) void cvt_f32_f16(
    const float4* __restrict__ in, ushort4* __restrict__ out)
{
    int i = blockIdx.x * 256 + threadIdx.x;
    float4 f = in[i];
    ushort4 o;
    o.x = f2h(f.x); o.y = f2h(f.y); o.z = f2h(f.z); o.w = f2h(f.w);
    out[i] = o;
}

// all six weight matrices: fp32 -> fp16 transposed, one dispatch (z=0..5).
__global__ __launch_bounds__(256) void wprep(
    const float* __restrict__ s0, const float* __restrict__ s1,
    const float* __restrict__ s2, const float* __restrict__ s3,
    const float* __restrict__ s4, const float* __restrict__ s5,
    unsigned short* __restrict__ W1T, unsigned short* __restrict__ W2T)
{
    const int C = 1024;
    const int z = blockIdx.z;
    const float* in = (z == 0) ? s0 : (z == 1) ? s1 : (z == 2) ? s2
                    : (z == 3) ? s3 : (z == 4) ? s4 : s5;
    unsigned short* out = (z < 3) ? (W1T + (long long)z * C * C)
                                  : (W2T + (long long)(z - 3) * C * C);
    __shared__ unsigned short tile[32][33];
    const int bx = blockIdx.x * 32;  // col base
    const int by = blockIdx.y * 32;  // row base
    const int x = threadIdx.x;
    for (int y = threadIdx.y; y < 32; y += 8)
        tile[y][x] = f2h(in[(long long)(by + y) * C + (bx + x)]);
    __syncthreads();
    for (int y = threadIdx.y; y < 32; y += 8)
        out[(long long)(bx + y) * C + (by + x)] = tile[x][y];
}

// wide fp16 transpose: 64x64 tiles, ushort4 (8B) loads AND stores.
// grid (cols/64, rows/64, NB); out[col][row] = in[row][col].
__global__ __launch_bounds__(256) void transpose64_f16(
    const unsigned short* __restrict__ in,
    unsigned short* __restrict__ out,
    int rows, int cols,
    long long sIn, long long sOut)
{
    __shared__ unsigned short tile[64][68];  // stride 68 shorts = 136 B (8B-aligned)
    const unsigned short* ip = in  + (long long)blockIdx.z * sIn;
    unsigned short*       op = out + (long long)blockIdx.z * sOut;
    const int bx = blockIdx.x * 64;  // col base
    const int by = blockIdx.y * 64;  // row base
    const int tid = threadIdx.x;
    const int rsub = tid >> 4;        // 0..15
    const int c4   = (tid & 15) * 4;  // 0,4,..,60
    #pragma unroll
    for (int it = 0; it < 4; it++) {
        const int r = it * 16 + rsub;
        ushort4 v = *(const ushort4*)&ip[(long long)(by + r) * cols + (bx + c4)];
        tile[r][c4]     = v.x;
        tile[r][c4 + 1] = v.y;
        tile[r][c4 + 2] = v.z;
        tile[r][c4 + 3] = v.w;
    }
    __syncthreads();
    #pragma unroll
    for (int it = 0; it < 4; it++) {
        const int cc = it * 16 + rsub;  // out row = in col
        ushort4 v;
        v.x = tile[c4][cc];
        v.y = tile[c4 + 1][cc];
        v.z = tile[c4 + 2][cc];
        v.w = tile[c4 + 3][cc];
        *(ushort4*)&op[(long long)(bx + cc) * rows + (by + c4)] = v;
    }
}

// one 256-thread block per row of 1024; fp16 in, fp32 params, fp32 out
__global__ __launch_bounds__(256) void layernorm_h(
    const unsigned short* __restrict__ X,
    const float* __restrict__ W,
    const float* __restrict__ Bv,
    float* __restrict__ Y)
{
    const int row = blockIdx.x;
    const int tid = threadIdx.x;
    ushort4 u = ((const ushort4*)(X + (long long)row * 1024))[tid];
    float f0 = h2f(u.x), f1 = h2f(u.y), f2 = h2f(u.z), f3 = h2f(u.w);
    float s  = f0 + f1 + f2 + f3;
    float ss = f0 * f0 + f1 * f1 + f2 * f2 + f3 * f3;
    #pragma unroll
    for (int off = 32; off > 0; off >>= 1) {
        s  += __shfl_down(s, off);
        ss += __shfl_down(ss, off);
    }
    __shared__ float red[2][4];
    const int wv = tid >> 6;
    if ((tid & 63) == 0) { red[0][wv] = s; red[1][wv] = ss; }
    __syncthreads();
    float S  = red[0][0] + red[0][1] + red[0][2] + red[0][3];
    float SS = red[1][0] + red[1][1] + red[1][2] + red[1][3];
    float mu  = S * (1.f / 1024.f);
    float var = SS * (1.f / 1024.f) - mu * mu;
    float rs  = rsqrtf(var + 1e-5f);
    float4 w4 = ((const float4*)W)[tid];
    float4 b4 = ((const float4*)Bv)[tid];
    float4 o;
    o.x = (f0 - mu) * rs * w4.x + b4.x;
    o.y = (f1 - mu) * rs * w4.y + b4.y;
    o.z = (f2 - mu) * rs * w4.z + b4.z;
    o.w = (f3 - mu) * rs * w4.w + b4.w;
    ((float4*)(Y + (long long)row * 1024))[tid] = o;
}

extern "C" void kernel_launch(void* const* d_in, const int* in_sizes, int n_in,
                              void* d_out, int out_size, void* d_ws, size_t ws_size,
                              hipStream_t stream)
{
    const int C  = 1024;
    const int T  = 2048;
    const int NB = 8;
    const int MT = NB * T;  // 16384 rows

    const float* x = (const float*)d_in[0];
    const float* W1q = (const float*)d_in[1];
    const float* b1q = (const float*)d_in[2];
    const float* W2q = (const float*)d_in[3];
    const float* b2q = (const float*)d_in[4];
    const float* W1k = (const float*)d_in[5];
    const float* b1k = (const float*)d_in[6];
    const float* W2k = (const float*)d_in[7];
    const float* b2k = (const float*)d_in[8];
    const float* W1v = (const float*)d_in[9];
    const float* b1v = (const float*)d_in[10];
    const float* W2v = (const float*)d_in[11];
    const float* b2v = (const float*)d_in[12];
    const float* lnw = (const float*)d_in[13];
    const float* lnb = (const float*)d_in[14];

    char* wsp = (char*)d_ws;
    auto take = [&](size_t bytes) {
        char* p = wsp;
        wsp += (bytes + 255) & ~(size_t)255;
        return p;
    };

    const size_t MATE = (size_t)MT * C;  // elements per [16384][1024] matrix

    unsigned short* W1T  = (unsigned short*)take((size_t)3 * C * C * 2);
    unsigned short* W2T  = (unsigned short*)take((size_t)3 * C * C * 2);
    unsigned short* xb   = (unsigned short*)take(MATE * 2);
    unsigned short* qkv  = (unsigned short*)take(3 * MATE * 2);  // q,k,v contiguous
    unsigned short* hreg = (unsigned short*)take(3 * MATE * 2);  // h; later scb+opre
    unsigned short* qb   = qkv;
    unsigned short* kb   = qkv + MATE;
    unsigned short* vb   = qkv + 2 * MATE;
    unsigned short* vT   = xb;                               // xb dead after MLP1
    unsigned short* scb  = hreg;                             // 8*T*T = 2*MATE elems
    unsigned short* opre = hreg + (size_t)NB * T * T;        // MATE elems — exact fit

    // x: fp32 -> fp16
    cvt_f32_f16<<<dim3(MT * C / 1024, 1, 1), dim3(256, 1, 1), 0, stream>>>(
        (const float4*)x, (ushort4*)xb);

    // all weights: fp32 -> fp16 transposed, one dispatch
    wprep<<<dim3(C / 32, C / 32, 6), dim3(32, 8, 1), 0, stream>>>(
        W1q, W1k, W1v, W2q, W2k, W2v, W1T, W2T);

    dim3 blk(256, 1, 1);

    // MLP GEMM1 (z = head): h_z = GELU(x @ W1_z + b1_z)   grid (M,N,z)
    gemm_bt<OP_BIAS_GELU, false, false, false, false><<<dim3(MT / BM, C / BN, 3), blk, 0, stream>>>(
        xb, W1T, hreg, b1q, b1k, b1v, MT, C, C,
        0, (long long)C * C, (long long)MATE, 1.f);

    // MLP GEMM2 (z = head): {q,k,v}_z = h_z @ W2_z + b2_z
    gemm_bt<OP_BIAS, false, false, false, false><<<dim3(MT / BM, C / BN, 3), blk, 0, stream>>>(
        hreg, W2T, qkv, b2q, b2k, b2v, MT, C, C,
        (long long)MATE, (long long)C * C, (long long)MATE, 1.f);

    // vT[b] = v[b]^T ([C][T] per batch) for the scores@v GEMM's BT operand
    transpose64_f16<<<dim3(C / 64, T / 64, NB), blk, 0, stream>>>(
        vb, vT, T, C, (long long)T * C, (long long)T * C);

    // scores = tril(q @ k^T) / sqrt(C*T); packed lower-triangle grid
    float inv_scale = 1.0f / sqrtf((float)C * (float)T);
    gemm_bt<OP_SCALE_MASK, false, true, false, false><<<dim3(136, NB, 1), blk, 0, stream>>>(
        qb, kb, scb, nullptr, nullptr, nullptr, T, T, C,
        (long long)T * C, (long long)T * C, (long long)T * T, inv_scale);

    // out_pre = scores @ v (K limited to bm+BM); PAIRM: each block does the
    // complementary pair (bm=p, bm=15-p) -> constant 2176 K-rows per block,
    // balanced per-CU regardless of block->CU assignment (R5).
    gemm_bt<OP_NONE, true, false, false, true><<<dim3(T / BM / 2, C / BN, NB), blk, 0, stream>>>(
        scb, vT, opre, nullptr, nullptr, nullptr, T, C, T,
        (long long)T * T, (long long)T * C, (long long)T * C, 1.f);

    layernorm_h<<<dim3(MT, 1, 1), dim3(256, 1, 1), 0, stream>>>(
        opre, lnw, lnb, (float*)d_out);
}

// Round 6
// 523.160 us; speedup vs baseline: 1.1584x; 1.0156x over previous
//
#include <hip/hip_runtime.h>
#include <math.h>

#define BM 128
#define BN 128
#define BK 64

typedef _Float16 f16x8 __attribute__((ext_vector_type(8)));
typedef __attribute__((ext_vector_type(4))) float f32x4;

typedef const __attribute__((address_space(1))) void* gas_ptr;
typedef __attribute__((address_space(3))) void* las_ptr;

enum { OP_NONE = 0, OP_BIAS_GELU = 1, OP_BIAS = 2, OP_SCALE_MASK = 3 };

__device__ __forceinline__ unsigned short f2h(float f) {
    _Float16 h = (_Float16)f;  // RTNE
    unsigned short u;
    __builtin_memcpy(&u, &h, 2);
    return u;
}
__device__ __forceinline__ float h2f(unsigned short u) {
    _Float16 h;
    __builtin_memcpy(&h, &u, 2);
    return (float)h;
}

// tanh-form GELU via sigmoid: ~7 VALU instrs vs ~50 for libm erff.
// Confirmed: absmax stays 0.03125 with this approximation.
__device__ __forceinline__ float fast_gelu(float x) {
    float x2 = x * x;
    float p  = x * (-1.5957691216f - 0.0713548164f * x2);  // = -2u
    float t  = __expf(p);                                  // e^{-2u}
    return x * __builtin_amdgcn_rcpf(1.0f + t);            // x * sigma(2u)
}

// C = A @ B, B given transposed (BT is [N][K] row-major). A [M][K], C [M][N].
// fp16 in/out, fp32 accumulate. BK=64 XOR-swizzled global_load_lds staging
// (0 bank conflicts). 16x16x32 MFMA (R3 A/B: 32x32x16 frag reads cost 1.26e7
// bank conflicts/dispatch, +21% dur -- 16x16 fr/quad is the conflict-free
// pattern). j-INNERMOST epilogue (R2/R4-validated: WRITE_SIZE at exact ideal,
// MLP 114->108 us). Body kept byte-identical to the R4 kernel: R5's in-loop
// wrapper (PAIRM) perturbed codegen of ALL instantiations (+5 us on MLPs,
// rule #19); pairing now lives in the separate gemm_pair kernel below.
// __launch_bounds__(256, 4): 4 blocks/CU co-residency hides prologue/epilogue
// and the per-K-step barrier drain; beat the 1-block/CU 256^2 8-phase at
// K=1024 (R1/R2).
template <int EPI, bool CAUSAL_K, bool TRI, bool REVM>
__global__ __launch_bounds__(256, 4) void gemm_bt(
    const unsigned short* __restrict__ A,
    const unsigned short* __restrict__ BT,
    unsigned short* __restrict__ Cw,
    const float* __restrict__ bias0,
    const float* __restrict__ bias1,
    const float* __restrict__ bias2,
    int M, int N, int K,
    long long sA, long long sB, long long sC,
    float scale)
{
    __shared__ __align__(16) unsigned short As[BM * BK];
    __shared__ __align__(16) unsigned short Bs[BN * BK];

    const int tid  = threadIdx.x;
    const int wave = tid >> 6;
    const int lane = tid & 63;

    int bm, bn, z;
    if (TRI) {
        // unrank t -> (i, j), j <= i, t = i(i+1)/2 + j
        const int t = blockIdx.x;
        int i = (int)((sqrtf(8.0f * t + 1.0f) - 1.0f) * 0.5f);
        while ((i + 1) * (i + 2) / 2 <= t) i++;
        while (i * (i + 1) / 2 > t) i--;
        const int j = t - i * (i + 1) / 2;
        bm = i * BM;
        bn = j * BN;
        z  = blockIdx.y;
    } else {
        bm = (REVM ? (gridDim.x - 1 - blockIdx.x) : blockIdx.x) * BM;
        bn = blockIdx.y * BN;
        z  = blockIdx.z;
    }

    const unsigned short* Ab = A  + (long long)z * sA;
    const unsigned short* Bb = BT + (long long)z * sB;
    unsigned short*       Cb = Cw + (long long)z * sC;
    const float* bias = nullptr;
    if (EPI == OP_BIAS || EPI == OP_BIAS_GELU)
        bias = (z == 0) ? bias0 : (z == 1) ? bias1 : bias2;

    const int wm = (wave >> 1) * 64;  // wave's 64x64 quadrant
    const int wn = (wave & 1) * 64;

    f32x4 acc[4][4];
    #pragma unroll
    for (int i = 0; i < 4; i++)
        #pragma unroll
        for (int j = 0; j < 4; j++)
            acc[i][j] = (f32x4){0.f, 0.f, 0.f, 0.f};

    int Keff = K;
    if (CAUSAL_K) {
        int kl = bm + BM;
        Keff = kl < K ? kl : K;
    }

    const int srow = lane >> 3;                          // row within 8-row slab
    const int gchw = ((lane & 7) ^ (srow & 7)) * 8;      // swizzled chunk, halfwords
    const int fr   = lane & 15;
    const int quad = lane >> 4;

    // per-lane global staging pointers; advance by BK per iter
    const unsigned short* pA = Ab + (long long)(bm + wave * 32 + srow) * K + gchw;
    const unsigned short* pB = Bb + (long long)(bn + wave * 32 + srow) * K + gchw;
    const long long rstep = 8ll * K;  // 8 rows between the 4 slabs of a wave

    for (int k0 = 0; k0 < Keff; k0 += BK) {
        #pragma unroll
        for (int s = 0; s < 4; ++s) {
            const int t = wave * 4 + s;
            __builtin_amdgcn_global_load_lds((gas_ptr)(const void*)(pA + s * rstep),
                                             (las_ptr)(void*)&As[t * 512 + lane * 8],
                                             16, 0, 0);
            __builtin_amdgcn_global_load_lds((gas_ptr)(const void*)(pB + s * rstep),
                                             (las_ptr)(void*)&Bs[t * 512 + lane * 8],
                                             16, 0, 0);
        }
        pA += BK;
        pB += BK;
        __syncthreads();  // drains vmcnt -> staged data visible

        #pragma unroll
        for (int kk = 0; kk < 2; ++kk) {
            f16x8 fa[4], fb[4];
            #pragma unroll
            for (int i = 0; i < 4; i++) {
                const int row  = wm + i * 16 + fr;
                const int slot = row * 8 + ((kk * 4 + quad) ^ (fr & 7));
                fa[i] = *(const f16x8*)&As[slot * 8];
            }
            #pragma unroll
            for (int j = 0; j < 4; j++) {
                const int row  = wn + j * 16 + fr;
                const int slot = row * 8 + ((kk * 4 + quad) ^ (fr & 7));
                fb[j] = *(const f16x8*)&Bs[slot * 8];
            }
            #pragma unroll
            for (int i = 0; i < 4; i++)
                #pragma unroll
                for (int j = 0; j < 4; j++)
                    acc[i][j] = __builtin_amdgcn_mfma_f32_16x16x32_f16(
                        fa[i], fb[j], acc[i][j], 0, 0, 0);
        }
        __syncthreads();  // protect LDS before next stage overwrites
    }

    // epilogue: C/D layout col=lane&15, row=(lane>>4)*4+reg  [m89/m91]
    // j INNERMOST: per (i,r), lanes cover cols [wn, wn+64) in 4 consecutive
    // 32B stores -> each 128B L2 line fully dirtied immediately.
    const int er = quad;
    const int ec = fr;
    float bj[4];
    if (EPI == OP_BIAS || EPI == OP_BIAS_GELU) {
        #pragma unroll
        for (int j = 0; j < 4; j++) bj[j] = bias[bn + wn + j * 16 + ec];
    }
    #pragma unroll
    for (int i = 0; i < 4; i++) {
        #pragma unroll
        for (int r = 0; r < 4; r++) {
            const int row = bm + wm + i * 16 + er * 4 + r;
            #pragma unroll
            for (int j = 0; j < 4; j++) {
                const int col = bn + wn + j * 16 + ec;
                float v = acc[i][j][r];
                if (EPI == OP_BIAS_GELU) {
                    v = fast_gelu(v + bj[j]);
                } else if (EPI == OP_BIAS) {
                    v += bj[j];
                } else if (EPI == OP_SCALE_MASK) {
                    v *= scale;
                    if (col > row) v = 0.f;
                }
                Cb[(long long)row * N + col] = f2h(v);
            }
        }
    }
}

// out_pre = scores @ v, causal K (Keff = bm+BM), complementary-pair balanced:
// block bx does bm-tiles {bx, 2*gridDim.x-1-bx} -> constant 17*128 K-rows per
// block regardless of block->CU assignment (R5: -17 us vs unbalanced).
// Separate kernel so the hot gemm_bt instantiations keep R4 codegen (rule #19).
__global__ __launch_bounds__(256, 4) void gemm_pair(
    const unsigned short* __restrict__ A,
    const unsigned short* __restrict__ BT,
    unsigned short* __restrict__ Cw,
    int M, int N, int K,
    long long sA, long long sB, long long sC)
{
    __shared__ __align__(16) unsigned short As[BM * BK];
    __shared__ __align__(16) unsigned short Bs[BN * BK];

    const int tid  = threadIdx.x;
    const int wave = tid >> 6;
    const int lane = tid & 63;

    const int wm = (wave >> 1) * 64;
    const int wn = (wave & 1) * 64;

    const int srow = lane >> 3;
    const int gchw = ((lane & 7) ^ (srow & 7)) * 8;
    const int fr   = lane & 15;
    const int quad = lane >> 4;

    const int z  = blockIdx.z;
    const int bn = blockIdx.y * BN;
    const unsigned short* Ab = A  + (long long)z * sA;
    const unsigned short* Bb = BT + (long long)z * sB;
    unsigned short*       Cb = Cw + (long long)z * sC;

    #pragma unroll 1
    for (int half = 0; half < 2; ++half) {
        const int mb = half ? (2 * (int)gridDim.x - 1 - (int)blockIdx.x)
                            : (int)blockIdx.x;
        const int bm = mb * BM;

        f32x4 acc[4][4];
        #pragma unroll
        for (int i = 0; i < 4; i++)
            #pragma unroll
            for (int j = 0; j < 4; j++)
                acc[i][j] = (f32x4){0.f, 0.f, 0.f, 0.f};

        int Keff = bm + BM;
        if (Keff > K) Keff = K;

        const unsigned short* pA = Ab + (long long)(bm + wave * 32 + srow) * K + gchw;
        const unsigned short* pB = Bb + (long long)(bn + wave * 32 + srow) * K + gchw;
        const long long rstep = 8ll * K;

        for (int k0 = 0; k0 < Keff; k0 += BK) {
            #pragma unroll
            for (int s = 0; s < 4; ++s) {
                const int t = wave * 4 + s;
                __builtin_amdgcn_global_load_lds((gas_ptr)(const void*)(pA + s * rstep),
                                                 (las_ptr)(void*)&As[t * 512 + lane * 8],
                                                 16, 0, 0);
                __builtin_amdgcn_global_load_lds((gas_ptr)(const void*)(pB + s * rstep),
                                                 (las_ptr)(void*)&Bs[t * 512 + lane * 8],
                                                 16, 0, 0);
            }
            pA += BK;
            pB += BK;
            __syncthreads();

            #pragma unroll
            for (int kk = 0; kk < 2; ++kk) {
                f16x8 fa[4], fb[4];
                #pragma unroll
                for (int i = 0; i < 4; i++) {
                    const int row  = wm + i * 16 + fr;
                    const int slot = row * 8 + ((kk * 4 + quad) ^ (fr & 7));
                    fa[i] = *(const f16x8*)&As[slot * 8];
                }
                #pragma unroll
                for (int j = 0; j < 4; j++) {
                    const int row  = wn + j * 16 + fr;
                    const int slot = row * 8 + ((kk * 4 + quad) ^ (fr & 7));
                    fb[j] = *(const f16x8*)&Bs[slot * 8];
                }
                #pragma unroll
                for (int i = 0; i < 4; i++)
                    #pragma unroll
                    for (int j = 0; j < 4; j++)
                        acc[i][j] = __builtin_amdgcn_mfma_f32_16x16x32_f16(
                            fa[i], fb[j], acc[i][j], 0, 0, 0);
            }
            __syncthreads();
        }

        const int er = quad;
        const int ec = fr;
        #pragma unroll
        for (int i = 0; i < 4; i++) {
            #pragma unroll
            for (int r = 0; r < 4; r++) {
                const int row = bm + wm + i * 16 + er * 4 + r;
                #pragma unroll
                for (int j = 0; j < 4; j++) {
                    const int col = bn + wn + j * 16 + ec;
                    Cb[(long long)row * N + col] = f2h(acc[i][j][r]);
                }
            }
        }
        // LDS reuse across halves race-free: last ds_reads precede the final
        // __syncthreads of the K-loop; epilogue touches no LDS.
    }
}

// fp32 -> fp16 elementwise (n divisible by 1024)
__global__ __launch_bounds__(256) void cvt_f32_f16(
    const float4* __restrict__ in, ushort4* __restrict__ out)
{
    int i = blockIdx.x * 256 + threadIdx.x;
    float4 f = in[i];
    ushort4 o;
    o.x = f2h(f.x); o.y = f2h(f.y); o.z = f2h(f.z); o.w = f2h(f.w);
    out[i] = o;
}

// all six weight matrices: fp32 -> fp16 transposed. R6: 64x64 tiles with
// float4 (16B) loads and ushort4 (8B) stores -- same structure as the proven
// transpose64_f16 (was: 32x32 tiles, scalar fp32 loads, 6144 tiny blocks).
__global__ __launch_bounds__(256) void wprep64(
    const float* __restrict__ s0, const float* __restrict__ s1,
    const float* __restrict__ s2, const float* __restrict__ s3,
    const float* __restrict__ s4, const float* __restrict__ s5,
    unsigned short* __restrict__ W1T, unsigned short* __restrict__ W2T)
{
    const int C = 1024;
    const int z = blockIdx.z;
    const float* in = (z == 0) ? s0 : (z == 1) ? s1 : (z == 2) ? s2
                    : (z == 3) ? s3 : (z == 4) ? s4 : s5;
    unsigned short* out = (z < 3) ? (W1T + (long long)z * C * C)
                                  : (W2T + (long long)(z - 3) * C * C);
    __shared__ unsigned short tile[64][68];  // stride 68 shorts (8B-aligned)
    const int bx = blockIdx.x * 64;  // col base
    const int by = blockIdx.y * 64;  // row base
    const int tid = threadIdx.x;
    const int rsub = tid >> 4;        // 0..15
    const int c4   = (tid & 15) * 4;  // 0,4,..,60
    #pragma unroll
    for (int it = 0; it < 4; it++) {
        const int r = it * 16 + rsub;
        float4 v = *(const float4*)&in[(long long)(by + r) * C + (bx + c4)];
        tile[r][c4]     = f2h(v.x);
        tile[r][c4 + 1] = f2h(v.y);
        tile[r][c4 + 2] = f2h(v.z);
        tile[r][c4 + 3] = f2h(v.w);
    }
    __syncthreads();
    #pragma unroll
    for (int it = 0; it < 4; it++) {
        const int cc = it * 16 + rsub;  // out row = in col
        ushort4 v;
        v.x = tile[c4][cc];
        v.y = tile[c4 + 1][cc];
        v.z = tile[c4 + 2][cc];
        v.w = tile[c4 + 3][cc];
        *(ushort4*)&out[(long long)(bx + cc) * C + (by + c4)] = v;
    }
}

// wide fp16 transpose: 64x64 tiles, ushort4 (8B) loads AND stores.
// grid (cols/64, rows/64, NB); out[col][row] = in[row][col].
__global__ __launch_bounds__(256) void transpose64_f16(
    const unsigned short* __restrict__ in,
    unsigned short* __restrict__ out,
    int rows, int cols,
    long long sIn, long long sOut)
{
    __shared__ unsigned short tile[64][68];  // stride 68 shorts = 136 B (8B-aligned)
    const unsigned short* ip = in  + (long long)blockIdx.z * sIn;
    unsigned short*       op = out + (long long)blockIdx.z * sOut;
    const int bx = blockIdx.x * 64;  // col base
    const int by = blockIdx.y * 64;  // row base
    const int tid = threadIdx.x;
    const int rsub = tid >> 4;        // 0..15
    const int c4   = (tid & 15) * 4;  // 0,4,..,60
    #pragma unroll
    for (int it = 0; it < 4; it++) {
        const int r = it * 16 + rsub;
        ushort4 v = *(const ushort4*)&ip[(long long)(by + r) * cols + (bx + c4)];
        tile[r][c4]     = v.x;
        tile[r][c4 + 1] = v.y;
        tile[r][c4 + 2] = v.z;
        tile[r][c4 + 3] = v.w;
    }
    __syncthreads();
    #pragma unroll
    for (int it = 0; it < 4; it++) {
        const int cc = it * 16 + rsub;  // out row = in col
        ushort4 v;
        v.x = tile[c4][cc];
        v.y = tile[c4 + 1][cc];
        v.z = tile[c4 + 2][cc];
        v.w = tile[c4 + 3][cc];
        *(ushort4*)&op[(long long)(bx + cc) * rows + (by + c4)] = v;
    }
}

// R6: wave-per-row layernorm. 4 rows per 256-thread block; each lane holds 16
// elems; pure __shfl_xor butterfly reduce -- no LDS, no __syncthreads (was:
// one block per row with 2-level LDS reduce + 2 barriers, 16384 blocks).
__global__ __launch_bounds__(256) void layernorm_w(
    const unsigned short* __restrict__ X,
    const float* __restrict__ W,
    const float* __restrict__ Bv,
    float* __restrict__ Y)
{
    const int wave = threadIdx.x >> 6;
    const int lane = threadIdx.x & 63;
    const long long row = (long long)blockIdx.x * 4 + wave;
    const unsigned short* xr = X + row * 1024;
    float f[16];
    float s = 0.f, ss = 0.f;
    #pragma unroll
    for (int t = 0; t < 4; t++) {
        ushort4 u = *(const ushort4*)&xr[lane * 4 + t * 256];
        float a = h2f(u.x), b = h2f(u.y), c = h2f(u.z), d = h2f(u.w);
        f[t * 4 + 0] = a; f[t * 4 + 1] = b; f[t * 4 + 2] = c; f[t * 4 + 3] = d;
        s  += a + b + c + d;
        ss += a * a + b * b + c * c + d * d;
    }
    #pragma unroll
    for (int off = 32; off >= 1; off >>= 1) {
        s  += __shfl_xor(s, off);
        ss += __shfl_xor(ss, off);
    }
    const float mu  = s * (1.f / 1024.f);
    const float var = ss * (1.f / 1024.f) - mu * mu;
    const float rs  = rsqrtf(var + 1e-5f);
    #pragma unroll
    for (int t = 0; t < 4; t++) {
        float4 w4 = *(const float4*)&W[lane * 4 + t * 256];
        float4 b4 = *(const float4*)&Bv[lane * 4 + t * 256];
        float4 o;
        o.x = (f[t * 4 + 0] - mu) * rs * w4.x + b4.x;
        o.y = (f[t * 4 + 1] - mu) * rs * w4.y + b4.y;
        o.z = (f[t * 4 + 2] - mu) * rs * w4.z + b4.z;
        o.w = (f[t * 4 + 3] - mu) * rs * w4.w + b4.w;
        *(float4*)&Y[row * 1024 + lane * 4 + t * 256] = o;
    }
}

extern "C" void kernel_launch(void* const* d_in, const int* in_sizes, int n_in,
                              void* d_out, int out_size, void* d_ws, size_t ws_size,
                              hipStream_t stream)
{
    const int C  = 1024;
    const int T  = 2048;
    const int NB = 8;
    const int MT = NB * T;  // 16384 rows

    const float* x = (const float*)d_in[0];
    const float* W1q = (const float*)d_in[1];
    const float* b1q = (const float*)d_in[2];
    const float* W2q = (const float*)d_in[3];
    const float* b2q = (const float*)d_in[4];
    const float* W1k = (const float*)d_in[5];
    const float* b1k = (const float*)d_in[6];
    const float* W2k = (const float*)d_in[7];
    const float* b2k = (const float*)d_in[8];
    const float* W1v = (const float*)d_in[9];
    const float* b1v = (const float*)d_in[10];
    const float* W2v = (const float*)d_in[11];
    const float* b2v = (const float*)d_in[12];
    const float* lnw = (const float*)d_in[13];
    const float* lnb = (const float*)d_in[14];

    char* wsp = (char*)d_ws;
    auto take = [&](size_t bytes) {
        char* p = wsp;
        wsp += (bytes + 255) & ~(size_t)255;
        return p;
    };

    const size_t MATE = (size_t)MT * C;  // elements per [16384][1024] matrix

    unsigned short* W1T  = (unsigned short*)take((size_t)3 * C * C * 2);
    unsigned short* W2T  = (unsigned short*)take((size_t)3 * C * C * 2);
    unsigned short* xb   = (unsigned short*)take(MATE * 2);
    unsigned short* qkv  = (unsigned short*)take(3 * MATE * 2);  // q,k,v contiguous
    unsigned short* hreg = (unsigned short*)take(3 * MATE * 2);  // h; later scb+opre
    unsigned short* qb   = qkv;
    unsigned short* kb   = qkv + MATE;
    unsigned short* vb   = qkv + 2 * MATE;
    unsigned short* vT   = xb;                               // xb dead after MLP1
    unsigned short* scb  = hreg;                             // 8*T*T = 2*MATE elems
    unsigned short* opre = hreg + (size_t)NB * T * T;        // MATE elems — exact fit

    // x: fp32 -> fp16
    cvt_f32_f16<<<dim3(MT * C / 1024, 1, 1), dim3(256, 1, 1), 0, stream>>>(
        (const float4*)x, (ushort4*)xb);

    // all weights: fp32 -> fp16 transposed, one dispatch (64x64 vectorized)
    wprep64<<<dim3(C / 64, C / 64, 6), dim3(256, 1, 1), 0, stream>>>(
        W1q, W1k, W1v, W2q, W2k, W2v, W1T, W2T);

    dim3 blk(256, 1, 1);

    // MLP GEMM1 (z = head): h_z = GELU(x @ W1_z + b1_z)   grid (M,N,z)
    gemm_bt<OP_BIAS_GELU, false, false, false><<<dim3(MT / BM, C / BN, 3), blk, 0, stream>>>(
        xb, W1T, hreg, b1q, b1k, b1v, MT, C, C,
        0, (long long)C * C, (long long)MATE, 1.f);

    // MLP GEMM2 (z = head): {q,k,v}_z = h_z @ W2_z + b2_z
    gemm_bt<OP_BIAS, false, false, false><<<dim3(MT / BM, C / BN, 3), blk, 0, stream>>>(
        hreg, W2T, qkv, b2q, b2k, b2v, MT, C, C,
        (long long)MATE, (long long)C * C, (long long)MATE, 1.f);

    // vT[b] = v[b]^T ([C][T] per batch) for the scores@v GEMM's BT operand
    transpose64_f16<<<dim3(C / 64, T / 64, NB), blk, 0, stream>>>(
        vb, vT, T, C, (long long)T * C, (long long)T * C);

    // scores = tril(q @ k^T) / sqrt(C*T); packed lower-triangle grid
    float inv_scale = 1.0f / sqrtf((float)C * (float)T);
    gemm_bt<OP_SCALE_MASK, false, true, false><<<dim3(136, NB, 1), blk, 0, stream>>>(
        qb, kb, scb, nullptr, nullptr, nullptr, T, T, C,
        (long long)T * C, (long long)T * C, (long long)T * T, inv_scale);

    // out_pre = scores @ v; complementary-pair balanced (constant per-block work)
    gemm_pair<<<dim3(T / BM / 2, C / BN, NB), blk, 0, stream>>>(
        scb, vT, opre, T, C, T,
        (long long)T * T, (long long)T * C, (long long)T * C);

    layernorm_w<<<dim3(MT / 4, 1, 1), dim3(256, 1, 1), 0, stream>>>(
        opre, lnw, lnb, (float*)d_out);
}